// Round 6
// baseline (3536.692 us; speedup 1.0000x reference)
//
#include <hip/hip_runtime.h>

typedef unsigned short ushort_t;
typedef __attribute__((ext_vector_type(8))) short bf16x8;
typedef __attribute__((ext_vector_type(4))) float f32x4;

__device__ __forceinline__ ushort_t f2bf(float f) {
    union { float f; unsigned u; } v; v.f = f;
    unsigned r = v.u + 0x7FFFu + ((v.u >> 16) & 1u);
    return (ushort_t)(r >> 16);
}
__device__ __forceinline__ float siluf(float x) { return x / (1.f + __expf(-x)); }
__device__ __forceinline__ float sigm(float x)  { return 1.f / (1.f + __expf(-x)); }

__device__ __forceinline__ void gl2lds16(const void* g, void* l) {
    __builtin_amdgcn_global_load_lds(
        (__attribute__((address_space(1))) void*)(const_cast<void*>(g)),
        (__attribute__((address_space(3))) void*)(l), 16, 0, 0);
}

// Weight layout "WTS": W^T stored kslab-major: [kslab 0..15][n 0..511][32 k]
// with 16B-chunk swizzle chunk' = chunk ^ (n&3). Each kslab = 32 KB contiguous.
__device__ __forceinline__ size_t wts_off(int n, int k) {
    return (size_t)((k >> 5) * 16384) + n * 32
         + ((((k >> 3) & 3) ^ (n & 3)) * 8) + (k & 7);
}

// ---------------- fused weight transpose + PE-constant precompute ----------------
__global__ void k_pt(const float* W_epe, const float* W_ev1, const float* W_ev2,
                     const float* t_pe, const float* W_vpe, const float* b_vpe,
                     const float* b_epe,
                     ushort_t* WT_epe, ushort_t* WT_c, ushort_t* WT_ev2,
                     float* c_v, float* c_e) {
    int n = blockIdx.x, mat = blockIdx.y, t = threadIdx.x;
    if (mat == 3) {
        if (n < 4) {
            int b = n;
            for (int col = t; col < 512; col += 256) {
                float acc = b_epe[col];
                for (int u = 0; u < 100; ++u) acc += t_pe[b*100+u] * W_epe[(512+u)*512 + col];
                c_e[b*512 + col] = acc;
            }
            {
                float acc = b_vpe[t];
                for (int u = 0; u < 100; ++u) acc += t_pe[b*100+u] * W_vpe[(456+u)*256 + t];
                c_v[b*256 + t] = acc;
            }
        }
        return;
    }
    const float* src; ushort_t* dst;
    if (mat == 0)      { src = W_epe;            dst = WT_epe; }
    else if (mat == 1) { src = W_ev1 + 512*512;  dst = WT_c;   }
    else               { src = W_ev2;            dst = WT_ev2; }
    for (int k = t; k < 512; k += 256)
        dst[wts_off(n, k)] = f2bf(src[k*512 + n]);
}

// ---------------- node feature kernels ----------------
__global__ void k_node_v(const float* v_f, const float* p_pe, const float* W_vpe,
                         const float* c_v, float* v) {
    __shared__ float rv[4][256];
    __shared__ float rp[4][200];
    int r0 = blockIdx.x * 4, t = threadIdx.x;
    for (int rr = 0; rr < 4; ++rr) {
        rv[rr][t] = v_f[(r0+rr)*256 + t];
        if (t < 200) rp[rr][t] = p_pe[(r0+rr)*200 + t];
    }
    __syncthreads();
    int b = r0 >> 7;
    float acc[4];
    float cv = c_v[b*256 + t];
    for (int rr = 0; rr < 4; ++rr) acc[rr] = cv;
    for (int k = 0; k < 256; ++k) {
        float w = W_vpe[k*256 + t];
        #pragma unroll
        for (int rr = 0; rr < 4; ++rr) acc[rr] += rv[rr][k] * w;
    }
    for (int k = 0; k < 200; ++k) {
        float w = W_vpe[(256+k)*256 + t];
        #pragma unroll
        for (int rr = 0; rr < 4; ++rr) acc[rr] += rp[rr][k] * w;
    }
    for (int rr = 0; rr < 4; ++rr) v[(r0+rr)*256 + t] = siluf(acc[rr]);
}

// which==2 writes silu(v@W_self+b_self) straight into v2buf (k_chain atomicAdds onto it)
__global__ void k_node_proj(const float* v,
                            const float* W_q, const float* b_q,
                            const float* W_k, const float* b_k,
                            const float* W_self, const float* b_self,
                            const float* W_ev1, const float* b_ev1,
                            float* q, float* kk, float* vs, float* P, float* Q) {
    __shared__ float rv[4][256];
    int r0 = blockIdx.x * 4, which = blockIdx.y, t = threadIdx.x;
    for (int rr = 0; rr < 4; ++rr) rv[rr][t] = v[(r0+rr)*256 + t];
    __syncthreads();
    const float* W; const float* bias = nullptr; float* out; bool do_silu = false;
    if (which == 0)      { W = W_q;    bias = b_q;    out = q;  }
    else if (which == 1) { W = W_k;    bias = b_k;    out = kk; }
    else if (which == 2) { W = W_self; bias = b_self; out = vs; do_silu = true; }
    else if (which == 3) { W = W_ev1;  bias = b_ev1;  out = P;  }
    else                 { W = W_ev1 + 256*512;       out = Q;  }
    float acc[4][2] = {};
    for (int k = 0; k < 256; ++k) {
        float w0 = W[k*512 + t];
        float w1 = W[k*512 + t + 256];
        #pragma unroll
        for (int rr = 0; rr < 4; ++rr) {
            acc[rr][0] += rv[rr][k] * w0;
            acc[rr][1] += rv[rr][k] * w1;
        }
    }
    float bb0 = bias ? bias[t] : 0.f;
    float bb1 = bias ? bias[t + 256] : 0.f;
    for (int rr = 0; rr < 4; ++rr) {
        float x0 = acc[rr][0] + bb0;
        float x1 = acc[rr][1] + bb1;
        if (do_silu) { x0 = siluf(x0); x1 = siluf(x1); }
        out[(r0+rr)*512 + t]       = x0;
        out[(r0+rr)*512 + t + 256] = x1;
    }
}

// normalized attention weights: anorm[b,i,j,g] (4*128*128*32 fp32)
__global__ __launch_bounds__(256) void k_attw(const float* q, const float* kmat,
                                              const float* emask, float* anorm) {
    int bi = blockIdx.x; int b = bi >> 7, i = bi & 127;
    int t = threadIdx.x;
    __shared__ __align__(16) float qrow[512];
    __shared__ float s[128][33];
    __shared__ float invd[32];
    qrow[t]       = q[(size_t)bi*512 + t];
    qrow[t + 256] = q[(size_t)bi*512 + t + 256];
    __syncthreads();
    {
        int j = t >> 1, g0 = (t & 1) * 16;
        const float* kr = kmat + ((size_t)b*128 + j) * 512;
        float msk = emask[(size_t)b*16384 + i*128 + j];
        for (int gg = 0; gg < 16; ++gg) {
            int g = g0 + gg;
            const float4* k4 = (const float4*)(kr + g*16);
            const float4* q4 = (const float4*)(qrow + g*16);
            float acc = 0.f;
            #pragma unroll
            for (int c = 0; c < 4; ++c) {
                float4 kv = k4[c], qv = q4[c];
                acc += kv.x*qv.x + kv.y*qv.y + kv.z*qv.z + kv.w*qv.w;
            }
            s[j][g] = sigm(acc * 0.14433756729740645f) * msk;
        }
    }
    __syncthreads();
    if (t < 32) {
        float d = 1e-6f;
        for (int j = 0; j < 128; ++j) d += s[j][t];
        invd[t] = 1.f / d;
    }
    __syncthreads();
    float* dst = anorm + (size_t)bi * 4096;
    for (int idx = t; idx < 4096; idx += 256) {
        int j = idx >> 5, g = idx & 31;
        dst[idx] = s[j][g] * invd[g];
    }
}

// ---------------- fused 3-GEMM chain (per block: 64 rows end-to-end) ----------------
// C0 = silu(ef@W0 + c_e) ; C1 = silu(C0@W1 + P + Q) ; C2 = C1@W2 + b_ev2
// out_e = C2 ; v2 += sum_j anorm*C2 (atomicAdd onto node_proj-initialized v2buf).
// LDS: aL 64 KB (TS-swizzled 64x512 bf16 A) + bL 2x32 KB weight dbuf = 128 KB.
// R5 fix: the R5 version spilled acc[4][4] to scratch (11.8 GB HBM traffic,
// 3.3 ms). Two pressure cuts: (a) __launch_bounds__(512, 2) declares the true
// 1-block/CU occupancy so the allocator may use ~256 VGPRs instead of capping
// at 112 and spilling; (b) epi1 reads Qbuf directly per element instead of
// prefetching a 64-float qv[][][] array across the epilogue.
__global__ __launch_bounds__(512, 2) void k_chain(const float* ef,
                                               const ushort_t* W0, const ushort_t* W1,
                                               const ushort_t* W2,
                                               const float* c_e, const float* Pbuf,
                                               const float* Qbuf, const float* b_ev2,
                                               const float* anorm,
                                               float* out_e, float* v2buf) {
    __shared__ __align__(16) ushort_t smem[65536];   // 128 KB: aL[0,32768) bL[32768,65536)
    int lin = blockIdx.x;
    int mt = (lin & 7) * 128 + (lin >> 3);           // 0..1023, XCD-chunked
    int r0 = mt * 64;                                 // global edge-row base
    int bi = mt >> 1;                                 // b*128 + i
    int b_ = mt >> 8;                                 // batch
    int half = mt & 1;                                // which 64-j half of (b,i)
    int t = threadIdx.x;
    int wv = t >> 6, lane = t & 63;
    int wn = wv * 64;                                 // wave's 64-col slice
    int ml = lane & 15, quad = lane >> 4;
    int qs = (quad ^ (ml & 3)) * 8;
    f32x4 acc[4][4] = {};

    ushort_t* aL = smem;
    ushort_t* bL = smem + 32768;

    auto issueW = [&](const ushort_t* W, int sl) {
        int buf = sl & 1;
        #pragma unroll
        for (int s = 0; s < 4; ++s)
            gl2lds16(W + (size_t)sl * 16384 + s * 4096 + wv * 512 + lane * 8,
                     bL + buf * 16384 + s * 4096 + wv * 512);
    };
    auto compute = [&](int sl) {
        int buf = sl & 1;
        bf16x8 a[4], b[4];
        #pragma unroll
        for (int tm = 0; tm < 4; ++tm)
            a[tm] = *(const bf16x8*)(aL + sl * 2048 + (tm * 16 + ml) * 32 + qs);
        #pragma unroll
        for (int tn = 0; tn < 4; ++tn)
            b[tn] = *(const bf16x8*)(bL + buf * 16384 + (wn + tn * 16 + ml) * 32 + qs);
        #pragma unroll
        for (int tm = 0; tm < 4; ++tm)
            #pragma unroll
            for (int tn = 0; tn < 4; ++tn)
                acc[tm][tn] = __builtin_amdgcn_mfma_f32_16x16x32_bf16(a[tm], b[tn], acc[tm][tn], 0, 0, 0);
    };
    auto ring = [&](const ushort_t* W) {
        // entry: slab 0 resident (caller did issue(0); vmcnt(0); barrier)
        #pragma unroll
        for (int sl = 0; sl < 16; ++sl) {
            if (sl < 15) issueW(W, sl + 1);          // other buffer, free since prev barrier
            __builtin_amdgcn_s_setprio(1);
            compute(sl);
            __builtin_amdgcn_s_setprio(0);
            asm volatile("s_waitcnt vmcnt(0) lgkmcnt(0)" ::: "memory");
            __builtin_amdgcn_s_barrier();            // slab sl+1 ready; buf sl&1 free; aL reads drained
        }
    };

    // ---- stage 0: A = ef (fp32 -> bf16 in-kernel) ----
    issueW(W0, 0);
    #pragma unroll
    for (int i = 0; i < 16; ++i) {
        int qd  = i * 512 + t;                       // 64 rows * 128 f4-chunks
        int row = qd >> 7, k4 = (qd & 127) * 4;
        float4 f4 = *(const float4*)(ef + (size_t)(r0 + row) * 512 + k4);
        ushort_t* d = aL + (k4 >> 5) * 2048 + row * 32
                    + ((((k4 >> 3) & 3) ^ (row & 3)) * 8) + (k4 & 7);
        *(ushort4*)d = make_ushort4(f2bf(f4.x), f2bf(f4.y), f2bf(f4.z), f2bf(f4.w));
    }
    asm volatile("s_waitcnt vmcnt(0) lgkmcnt(0)" ::: "memory");
    __builtin_amdgcn_s_barrier();
    ring(W0);
    {   // epi0: C0 = silu(acc + c_e[b]) -> aL ; acc = 0
        float cv[4];
        #pragma unroll
        for (int tn = 0; tn < 4; ++tn) cv[tn] = c_e[b_ * 512 + wn + tn * 16 + ml];
        #pragma unroll
        for (int tm = 0; tm < 4; ++tm)
            #pragma unroll
            for (int tn = 0; tn < 4; ++tn) {
                int c = wn + tn * 16 + ml;
                #pragma unroll
                for (int r = 0; r < 4; ++r) {
                    int j = tm * 16 + quad * 4 + r;   // j&3 == r
                    float x = siluf(acc[tm][tn][r] + cv[tn]);
                    aL[(c >> 5) * 2048 + j * 32 + ((((c >> 3) & 3) ^ r) * 8) + (c & 7)] = f2bf(x);
                }
                acc[tm][tn] = (f32x4){0.f, 0.f, 0.f, 0.f};
            }
    }
    issueW(W1, 0);
    asm volatile("s_waitcnt vmcnt(0) lgkmcnt(0)" ::: "memory");
    __builtin_amdgcn_s_barrier();
    ring(W1);
    {   // epi1: C1 = silu(acc + P[b,i] + Q[b,j]) -> aL ; acc = 0
        //       (Q read directly per element: L2-hot, 64B-coalesced per quad;
        //        no qv[][][] prefetch -> no register-pressure spike)
        float Pv[4];
        #pragma unroll
        for (int tn = 0; tn < 4; ++tn) Pv[tn] = Pbuf[(size_t)bi * 512 + wn + tn * 16 + ml];
        #pragma unroll
        for (int tm = 0; tm < 4; ++tm)
            #pragma unroll
            for (int tn = 0; tn < 4; ++tn) {
                int c = wn + tn * 16 + ml;
                #pragma unroll
                for (int r = 0; r < 4; ++r) {
                    int j = tm * 16 + quad * 4 + r;
                    float qv = Qbuf[(size_t)(b_ * 128 + half * 64 + j) * 512 + c];
                    float x = siluf(acc[tm][tn][r] + Pv[tn] + qv);
                    aL[(c >> 5) * 2048 + j * 32 + ((((c >> 3) & 3) ^ r) * 8) + (c & 7)] = f2bf(x);
                }
                acc[tm][tn] = (f32x4){0.f, 0.f, 0.f, 0.f};
            }
    }
    issueW(W2, 0);
    asm volatile("s_waitcnt vmcnt(0) lgkmcnt(0)" ::: "memory");
    __builtin_amdgcn_s_barrier();
    ring(W2);
    {   // epi2: out_e = acc + b_ev2 ; v2 += anorm-weighted j-sum (atomic)
        float* awl = (float*)bL;                      // 2048 floats; ring fully drained
        ((float4*)awl)[t] = ((const float4*)(anorm + (size_t)bi * 4096 + half * 2048))[t];
        __syncthreads();
        float bv[4];
        #pragma unroll
        for (int tn = 0; tn < 4; ++tn) bv[tn] = b_ev2[wn + tn * 16 + ml];
        float partial[4] = {0.f, 0.f, 0.f, 0.f};
        #pragma unroll
        for (int tm = 0; tm < 4; ++tm)
            #pragma unroll
            for (int tn = 0; tn < 4; ++tn) {
                int c = wn + tn * 16 + ml;
                int g = c >> 4;
                #pragma unroll
                for (int r = 0; r < 4; ++r) {
                    int j = tm * 16 + quad * 4 + r;
                    float x = acc[tm][tn][r] + bv[tn];
                    out_e[(size_t)(r0 + j) * 512 + c] = x;
                    partial[tn] += awl[j * 32 + g] * x;
                }
            }
        #pragma unroll
        for (int tn = 0; tn < 4; ++tn) {
            float p = partial[tn];
            p += __shfl_down(p, 32);
            p += __shfl_down(p, 16);
            if (lane < 16)
                atomicAdd(v2buf + (size_t)bi * 512 + wn + tn * 16 + ml, p);
        }
    }
}

// ---------------- fused masked max-pool + output projection ----------------
__global__ __launch_bounds__(1024) void k_out(const float* v2, const float* vmask,
                                              const float* W_out, const float* b_out,
                                              float* out) {
    __shared__ float rv[2][512];          // this block's 2 rows
    __shared__ float vm[128];
    __shared__ float pm[2][512];
    __shared__ float pooled[512];
    __shared__ float red[2][2][256];      // [kc][row][col]
    __shared__ float cpred[2][256];
    int t = threadIdx.x;
    int r0 = blockIdx.x * 2, b = r0 >> 7;
    if (t < 128) vm[t] = -1e9f * (1.f - vmask[b*128 + t]);
    rv[t >> 9][t & 511] = v2[(size_t)(r0 + (t >> 9)) * 512 + (t & 511)];
    __syncthreads();
    {   // masked max-pool: col = t&511, row-chunk rc = t>>9 (64 rows each)
        int col = t & 511, rc = t >> 9;
        int i0 = rc * 64;
        const float* src = v2 + ((size_t)(b*128 + i0)) * 512 + col;
        float m = -1e30f;
        #pragma unroll 8
        for (int i = 0; i < 64; ++i)
            m = fmaxf(m, src[(size_t)i * 512] + vm[i0 + i]);
        pm[rc][col] = m;
    }
    __syncthreads();
    if (t < 512) pooled[t] = fmaxf(pm[0][t], pm[1][t]);
    __syncthreads();
    {   // projection: col = t&255, k-chunk kc = t>>8
        int col = t & 255, kc = t >> 8;
        if (kc < 2) {
            int k0 = kc * 256;
            float a0 = 0.f, a1 = 0.f;
            #pragma unroll 8
            for (int k = 0; k < 256; ++k) {
                float w = W_out[(size_t)(k0 + k) * 256 + col];
                a0 += rv[0][k0 + k] * w;
                a1 += rv[1][k0 + k] * w;
            }
            red[kc][0][col] = a0;
            red[kc][1][col] = a1;
        } else {
            int d0 = (kc - 2) * 256;
            float cp = 0.f;
            #pragma unroll 8
            for (int d = 0; d < 256; ++d)
                cp += pooled[d0 + d] * W_out[(size_t)(512 + d0 + d) * 256 + col];
            cpred[kc - 2][col] = cp;
        }
    }
    __syncthreads();
    if (t < 512) {
        int row = t >> 8, c = t & 255;
        float x = red[0][row][c] + red[1][row][c]
                + cpred[0][c] + cpred[1][c] + b_out[c];
        out[(size_t)(r0 + row) * 256 + c] = siluf(x);
    }
}

extern "C" void kernel_launch(void* const* d_in, const int* in_sizes, int n_in,
                              void* d_out, int out_size, void* d_ws, size_t ws_size,
                              hipStream_t stream) {
    const float* v_f    = (const float*)d_in[0];
    const float* e_f    = (const float*)d_in[1];
    const float* p_pe   = (const float*)d_in[2];
    const float* t_pe   = (const float*)d_in[3];
    const float* emask  = (const float*)d_in[4];
    const float* vmask  = (const float*)d_in[5];
    const float* W_vpe  = (const float*)d_in[6];
    const float* b_vpe  = (const float*)d_in[7];
    const float* W_epe  = (const float*)d_in[8];
    const float* b_epe  = (const float*)d_in[9];
    const float* W_ev1  = (const float*)d_in[10];
    const float* b_ev1  = (const float*)d_in[11];
    const float* W_ev2  = (const float*)d_in[12];
    const float* b_ev2  = (const float*)d_in[13];
    const float* W_q    = (const float*)d_in[14];
    const float* b_q    = (const float*)d_in[15];
    const float* W_k    = (const float*)d_in[16];
    const float* b_k    = (const float*)d_in[17];
    const float* W_self = (const float*)d_in[18];
    const float* b_self = (const float*)d_in[19];
    const float* W_out  = (const float*)d_in[20];
    const float* b_out  = (const float*)d_in[21];

    float* out_v = (float*)d_out;                 // (4,128,256)
    float* out_e = (float*)d_out + 131072;        // (4,16384,512)

    char* w = (char*)d_ws;
    ushort_t* WT_epe = (ushort_t*)w; w += 512*512*2;
    ushort_t* WT_c   = (ushort_t*)w; w += 512*512*2;
    ushort_t* WT_ev2 = (ushort_t*)w; w += 512*512*2;
    float* c_v   = (float*)w; w += 4*256*4;
    float* c_e   = (float*)w; w += 4*512*4;
    float* v     = (float*)w; w += 512*256*4;
    float* qbuf  = (float*)w; w += 512*512*4;
    float* kbuf  = (float*)w; w += 512*512*4;
    float* Pbuf  = (float*)w; w += 512*512*4;
    float* Qbuf  = (float*)w; w += 512*512*4;
    float* v2buf = (float*)w; w += 512*512*4;
    float* anorm = (float*)w; w += (size_t)4*128*128*32*4;   // 8 MB

    k_pt<<<dim3(512, 4), 256, 0, stream>>>(W_epe, W_ev1, W_ev2, t_pe, W_vpe, b_vpe, b_epe,
                                           WT_epe, WT_c, WT_ev2, c_v, c_e);
    k_node_v<<<128, 256, 0, stream>>>(v_f, p_pe, W_vpe, c_v, v);
    k_node_proj<<<dim3(128, 5), 256, 0, stream>>>(v, W_q, b_q, W_k, b_k, W_self, b_self,
                                                  W_ev1, b_ev1, qbuf, kbuf, v2buf, Pbuf, Qbuf);
    k_attw<<<512, 256, 0, stream>>>(qbuf, kbuf, emask, anorm);
    k_chain<<<1024, 512, 0, stream>>>(e_f, WT_epe, WT_c, WT_ev2, c_e, Pbuf, Qbuf,
                                      b_ev2, anorm, out_e, v2buf);
    k_out<<<256, 1024, 0, stream>>>(v2buf, vmask, W_out, b_out, out_v);
}

// Round 7
// 593.720 us; speedup vs baseline: 5.9568x; 5.9568x over previous
//
#include <hip/hip_runtime.h>

typedef unsigned short ushort_t;
typedef __attribute__((ext_vector_type(8))) short bf16x8;
typedef __attribute__((ext_vector_type(4))) float f32x4;

__device__ __forceinline__ ushort_t f2bf(float f) {
    union { float f; unsigned u; } v; v.f = f;
    unsigned r = v.u + 0x7FFFu + ((v.u >> 16) & 1u);
    return (ushort_t)(r >> 16);
}
__device__ __forceinline__ float siluf(float x) { return x / (1.f + __expf(-x)); }
__device__ __forceinline__ float sigm(float x)  { return 1.f / (1.f + __expf(-x)); }

__device__ __forceinline__ void gl2lds16(const void* g, void* l) {
    __builtin_amdgcn_global_load_lds(
        (__attribute__((address_space(1))) void*)(const_cast<void*>(g)),
        (__attribute__((address_space(3))) void*)(l), 16, 0, 0);
}

// Weight layout "WTS": W^T stored kslab-major: [kslab 0..15][n 0..511][32 k]
// with 16B-chunk swizzle chunk' = chunk ^ (n&3). Each kslab = 32 KB contiguous.
__device__ __forceinline__ size_t wts_off(int n, int k) {
    return (size_t)((k >> 5) * 16384) + n * 32
         + ((((k >> 3) & 3) ^ (n & 3)) * 8) + (k & 7);
}

// ---------------- fused weight transpose + PE-constant precompute ----------------
__global__ void k_pt(const float* W_epe, const float* W_ev1, const float* W_ev2,
                     const float* t_pe, const float* W_vpe, const float* b_vpe,
                     const float* b_epe,
                     ushort_t* WT_epe, ushort_t* WT_c, ushort_t* WT_ev2,
                     float* c_v, float* c_e) {
    int n = blockIdx.x, mat = blockIdx.y, t = threadIdx.x;
    if (mat == 3) {
        if (n < 4) {
            int b = n;
            for (int col = t; col < 512; col += 256) {
                float acc = b_epe[col];
                for (int u = 0; u < 100; ++u) acc += t_pe[b*100+u] * W_epe[(512+u)*512 + col];
                c_e[b*512 + col] = acc;
            }
            {
                float acc = b_vpe[t];
                for (int u = 0; u < 100; ++u) acc += t_pe[b*100+u] * W_vpe[(456+u)*256 + t];
                c_v[b*256 + t] = acc;
            }
        }
        return;
    }
    const float* src; ushort_t* dst;
    if (mat == 0)      { src = W_epe;            dst = WT_epe; }
    else if (mat == 1) { src = W_ev1 + 512*512;  dst = WT_c;   }
    else               { src = W_ev2;            dst = WT_ev2; }
    for (int k = t; k < 512; k += 256)
        dst[wts_off(n, k)] = f2bf(src[k*512 + n]);
}

// ---------------- node feature kernels ----------------
__global__ void k_node_v(const float* v_f, const float* p_pe, const float* W_vpe,
                         const float* c_v, float* v) {
    __shared__ float rv[4][256];
    __shared__ float rp[4][200];
    int r0 = blockIdx.x * 4, t = threadIdx.x;
    for (int rr = 0; rr < 4; ++rr) {
        rv[rr][t] = v_f[(r0+rr)*256 + t];
        if (t < 200) rp[rr][t] = p_pe[(r0+rr)*200 + t];
    }
    __syncthreads();
    int b = r0 >> 7;
    float acc[4];
    float cv = c_v[b*256 + t];
    for (int rr = 0; rr < 4; ++rr) acc[rr] = cv;
    for (int k = 0; k < 256; ++k) {
        float w = W_vpe[k*256 + t];
        #pragma unroll
        for (int rr = 0; rr < 4; ++rr) acc[rr] += rv[rr][k] * w;
    }
    for (int k = 0; k < 200; ++k) {
        float w = W_vpe[(256+k)*256 + t];
        #pragma unroll
        for (int rr = 0; rr < 4; ++rr) acc[rr] += rp[rr][k] * w;
    }
    for (int rr = 0; rr < 4; ++rr) v[(r0+rr)*256 + t] = siluf(acc[rr]);
}

// which==2 writes silu(v@W_self+b_self) straight into v2buf (k_chain atomicAdds onto it)
__global__ void k_node_proj(const float* v,
                            const float* W_q, const float* b_q,
                            const float* W_k, const float* b_k,
                            const float* W_self, const float* b_self,
                            const float* W_ev1, const float* b_ev1,
                            float* q, float* kk, float* vs, float* P, float* Q) {
    __shared__ float rv[4][256];
    int r0 = blockIdx.x * 4, which = blockIdx.y, t = threadIdx.x;
    for (int rr = 0; rr < 4; ++rr) rv[rr][t] = v[(r0+rr)*256 + t];
    __syncthreads();
    const float* W; const float* bias = nullptr; float* out; bool do_silu = false;
    if (which == 0)      { W = W_q;    bias = b_q;    out = q;  }
    else if (which == 1) { W = W_k;    bias = b_k;    out = kk; }
    else if (which == 2) { W = W_self; bias = b_self; out = vs; do_silu = true; }
    else if (which == 3) { W = W_ev1;  bias = b_ev1;  out = P;  }
    else                 { W = W_ev1 + 256*512;       out = Q;  }
    float acc[4][2] = {};
    for (int k = 0; k < 256; ++k) {
        float w0 = W[k*512 + t];
        float w1 = W[k*512 + t + 256];
        #pragma unroll
        for (int rr = 0; rr < 4; ++rr) {
            acc[rr][0] += rv[rr][k] * w0;
            acc[rr][1] += rv[rr][k] * w1;
        }
    }
    float bb0 = bias ? bias[t] : 0.f;
    float bb1 = bias ? bias[t + 256] : 0.f;
    for (int rr = 0; rr < 4; ++rr) {
        float x0 = acc[rr][0] + bb0;
        float x1 = acc[rr][1] + bb1;
        if (do_silu) { x0 = siluf(x0); x1 = siluf(x1); }
        out[(r0+rr)*512 + t]       = x0;
        out[(r0+rr)*512 + t + 256] = x1;
    }
}

// normalized attention weights: anorm[b,i,j,g] (4*128*128*32 fp32)
__global__ __launch_bounds__(256) void k_attw(const float* q, const float* kmat,
                                              const float* emask, float* anorm) {
    int bi = blockIdx.x; int b = bi >> 7, i = bi & 127;
    int t = threadIdx.x;
    __shared__ __align__(16) float qrow[512];
    __shared__ float s[128][33];
    __shared__ float invd[32];
    qrow[t]       = q[(size_t)bi*512 + t];
    qrow[t + 256] = q[(size_t)bi*512 + t + 256];
    __syncthreads();
    {
        int j = t >> 1, g0 = (t & 1) * 16;
        const float* kr = kmat + ((size_t)b*128 + j) * 512;
        float msk = emask[(size_t)b*16384 + i*128 + j];
        for (int gg = 0; gg < 16; ++gg) {
            int g = g0 + gg;
            const float4* k4 = (const float4*)(kr + g*16);
            const float4* q4 = (const float4*)(qrow + g*16);
            float acc = 0.f;
            #pragma unroll
            for (int c = 0; c < 4; ++c) {
                float4 kv = k4[c], qv = q4[c];
                acc += kv.x*qv.x + kv.y*qv.y + kv.z*qv.z + kv.w*qv.w;
            }
            s[j][g] = sigm(acc * 0.14433756729740645f) * msk;
        }
    }
    __syncthreads();
    if (t < 32) {
        float d = 1e-6f;
        for (int j = 0; j < 128; ++j) d += s[j][t];
        invd[t] = 1.f / d;
    }
    __syncthreads();
    float* dst = anorm + (size_t)bi * 4096;
    for (int idx = t; idx < 4096; idx += 256) {
        int j = idx >> 5, g = idx & 31;
        dst[idx] = s[j][g] * invd[g];
    }
}

// ---------------- fused 3-GEMM chain (per block: 64 rows end-to-end) ----------------
// C0 = silu(ef@W0 + c_e) ; C1 = silu(C0@W1 + P + Q) ; C2 = C1@W2 + b_ev2
// out_e = C2 ; v2 += sum_j anorm*C2 (atomicAdd onto node_proj-initialized v2buf).
// LDS: aL 64 KB (TS-swizzled 64x512 bf16 A) + bL 2x32 KB weight dbuf = 128 KB.
//
// R6 fix (scratch-alloca pathology): R5/R6 showed 11.8 GB HBM traffic and
// VGPR=112 — the acc[4][4] array was never SROA-promoted (alloca in scratch,
// re-stored/reloaded every slab around asm memory clobbers). This version
// forces register residency structurally: 16 NAMED f32x4 accumulators, no
// lambdas (macros only), no inline asm, no setprio — plain __syncthreads()
// double-buffer (T3-minimum schedule).

#define MFMA(A, B, C) __builtin_amdgcn_mfma_f32_16x16x32_bf16((A), (B), (C), 0, 0, 0)

#define ISSUE(W, SL) do {                                                     \
    const ushort_t* wsrc = (W) + (size_t)(SL) * 16384 + wv * 512 + lane * 8;  \
    ushort_t* wdst = bL + ((SL) & 1) * 16384 + wv * 512;                      \
    gl2lds16(wsrc,         wdst);                                             \
    gl2lds16(wsrc + 4096,  wdst + 4096);                                      \
    gl2lds16(wsrc + 8192,  wdst + 8192);                                      \
    gl2lds16(wsrc + 12288, wdst + 12288);                                     \
} while (0)

#define COMPUTE(SL) do {                                                      \
    const ushort_t* sA = aL + (SL) * 2048;                                    \
    const ushort_t* sB = bL + ((SL) & 1) * 16384;                             \
    bf16x8 a0 = *(const bf16x8*)(sA + (ml) * 32 + qs);                        \
    bf16x8 a1 = *(const bf16x8*)(sA + (16 + ml) * 32 + qs);                   \
    bf16x8 a2 = *(const bf16x8*)(sA + (32 + ml) * 32 + qs);                   \
    bf16x8 a3 = *(const bf16x8*)(sA + (48 + ml) * 32 + qs);                   \
    bf16x8 b0 = *(const bf16x8*)(sB + (wn + ml) * 32 + qs);                   \
    bf16x8 b1 = *(const bf16x8*)(sB + (wn + 16 + ml) * 32 + qs);              \
    bf16x8 b2 = *(const bf16x8*)(sB + (wn + 32 + ml) * 32 + qs);              \
    bf16x8 b3 = *(const bf16x8*)(sB + (wn + 48 + ml) * 32 + qs);              \
    acc00 = MFMA(a0, b0, acc00); acc01 = MFMA(a0, b1, acc01);                 \
    acc02 = MFMA(a0, b2, acc02); acc03 = MFMA(a0, b3, acc03);                 \
    acc10 = MFMA(a1, b0, acc10); acc11 = MFMA(a1, b1, acc11);                 \
    acc12 = MFMA(a1, b2, acc12); acc13 = MFMA(a1, b3, acc13);                 \
    acc20 = MFMA(a2, b0, acc20); acc21 = MFMA(a2, b1, acc21);                 \
    acc22 = MFMA(a2, b2, acc22); acc23 = MFMA(a2, b3, acc23);                 \
    acc30 = MFMA(a3, b0, acc30); acc31 = MFMA(a3, b1, acc31);                 \
    acc32 = MFMA(a3, b2, acc32); acc33 = MFMA(a3, b3, acc33);                 \
} while (0)

#define RING(W) do {                                                          \
    for (int sl = 0; sl < 16; ++sl) {                                         \
        if (sl < 15) ISSUE((W), sl + 1);                                      \
        COMPUTE(sl);                                                          \
        __syncthreads();                                                      \
    }                                                                         \
} while (0)

// epi0: aL[j][c] = bf16(silu(acc + cv)); acc = 0   (j0 multiple of 4 -> (j0+r)&3 == r)
#define EPI0(TM, TN, ACC, CV) {                                               \
    int c  = wn + (TN) * 16 + ml;                                             \
    int cb = (c >> 5) * 2048 + (c & 7);                                       \
    int cx = (c >> 3) & 3;                                                    \
    int j0 = (TM) * 16 + quad * 4;                                            \
    aL[cb + (j0+0)*32 + ((cx ^ 0) * 8)] = f2bf(siluf(ACC[0] + (CV)));         \
    aL[cb + (j0+1)*32 + ((cx ^ 1) * 8)] = f2bf(siluf(ACC[1] + (CV)));         \
    aL[cb + (j0+2)*32 + ((cx ^ 2) * 8)] = f2bf(siluf(ACC[2] + (CV)));         \
    aL[cb + (j0+3)*32 + ((cx ^ 3) * 8)] = f2bf(siluf(ACC[3] + (CV)));         \
    ACC = zero4; }

// epi1: aL[j][c] = bf16(silu(acc + Pv + Q[b,half*64+j,c])); acc = 0
#define EPI1(TM, TN, ACC, PV) {                                               \
    int c  = wn + (TN) * 16 + ml;                                             \
    int cb = (c >> 5) * 2048 + (c & 7);                                       \
    int cx = (c >> 3) & 3;                                                    \
    int j0 = (TM) * 16 + quad * 4;                                            \
    const float* qp = Qbuf + (size_t)(b_ * 128 + half * 64 + j0) * 512 + c;   \
    aL[cb + (j0+0)*32 + ((cx ^ 0) * 8)] = f2bf(siluf(ACC[0] + (PV) + qp[0]));    \
    aL[cb + (j0+1)*32 + ((cx ^ 1) * 8)] = f2bf(siluf(ACC[1] + (PV) + qp[512]));  \
    aL[cb + (j0+2)*32 + ((cx ^ 2) * 8)] = f2bf(siluf(ACC[2] + (PV) + qp[1024])); \
    aL[cb + (j0+3)*32 + ((cx ^ 3) * 8)] = f2bf(siluf(ACC[3] + (PV) + qp[1536])); \
    ACC = zero4; }

// epi2: out_e = acc + bv; partial += anorm-weight * value
#define EPI2(TM, TN, ACC, BV, PART) {                                         \
    int c  = wn + (TN) * 16 + ml;                                             \
    int g  = c >> 4;                                                          \
    int j0 = (TM) * 16 + quad * 4;                                            \
    float* op = out_e + (size_t)(r0 + j0) * 512 + c;                          \
    float x0 = ACC[0] + (BV); op[0]    = x0; PART += awl[(j0+0)*32 + g] * x0; \
    float x1 = ACC[1] + (BV); op[512]  = x1; PART += awl[(j0+1)*32 + g] * x1; \
    float x2 = ACC[2] + (BV); op[1024] = x2; PART += awl[(j0+2)*32 + g] * x2; \
    float x3 = ACC[3] + (BV); op[1536] = x3; PART += awl[(j0+3)*32 + g] * x3; }

__global__ __launch_bounds__(512) void k_chain(const float* ef,
                                               const ushort_t* W0, const ushort_t* W1,
                                               const ushort_t* W2,
                                               const float* c_e, const float* Pbuf,
                                               const float* Qbuf, const float* b_ev2,
                                               const float* anorm,
                                               float* out_e, float* v2buf) {
    __shared__ __align__(16) ushort_t smem[65536];   // 128 KB: aL[0,32768) bL[32768,65536)
    int lin = blockIdx.x;
    int mt = (lin & 7) * 128 + (lin >> 3);           // 0..1023, XCD-chunked
    int r0 = mt * 64;                                 // global edge-row base
    int bi = mt >> 1;                                 // b*128 + i
    int b_ = mt >> 8;                                 // batch
    int half = mt & 1;                                // which 64-j half of (b,i)
    int t = threadIdx.x;
    int wv = t >> 6, lane = t & 63;
    int wn = wv * 64;                                 // wave's 64-col slice
    int ml = lane & 15, quad = lane >> 4;
    int qs = (quad ^ (ml & 3)) * 8;

    const f32x4 zero4 = {0.f, 0.f, 0.f, 0.f};
    f32x4 acc00 = zero4, acc01 = zero4, acc02 = zero4, acc03 = zero4;
    f32x4 acc10 = zero4, acc11 = zero4, acc12 = zero4, acc13 = zero4;
    f32x4 acc20 = zero4, acc21 = zero4, acc22 = zero4, acc23 = zero4;
    f32x4 acc30 = zero4, acc31 = zero4, acc32 = zero4, acc33 = zero4;

    ushort_t* aL = smem;
    ushort_t* bL = smem + 32768;

    // ---- stage 0: A = ef (fp32 -> bf16 in-kernel) ----
    ISSUE(W0, 0);
    for (int i = 0; i < 16; ++i) {
        int qd  = i * 512 + t;                       // 64 rows * 128 f4-chunks
        int row = qd >> 7, k4 = (qd & 127) * 4;
        float4 f4 = *(const float4*)(ef + (size_t)(r0 + row) * 512 + k4);
        ushort_t* d = aL + (k4 >> 5) * 2048 + row * 32
                    + ((((k4 >> 3) & 3) ^ (row & 3)) * 8) + (k4 & 7);
        *(ushort4*)d = make_ushort4(f2bf(f4.x), f2bf(f4.y), f2bf(f4.z), f2bf(f4.w));
    }
    __syncthreads();                                  // ef in aL + W0 slab0 in bL
    RING(W0);
    {   // epi0: C0 = silu(acc + c_e[b]) -> aL (final ring barrier = WAR guard)
        float cv0 = c_e[b_ * 512 + wn +  0 + ml];
        float cv1 = c_e[b_ * 512 + wn + 16 + ml];
        float cv2 = c_e[b_ * 512 + wn + 32 + ml];
        float cv3 = c_e[b_ * 512 + wn + 48 + ml];
        EPI0(0,0,acc00,cv0) EPI0(0,1,acc01,cv1) EPI0(0,2,acc02,cv2) EPI0(0,3,acc03,cv3)
        EPI0(1,0,acc10,cv0) EPI0(1,1,acc11,cv1) EPI0(1,2,acc12,cv2) EPI0(1,3,acc13,cv3)
        EPI0(2,0,acc20,cv0) EPI0(2,1,acc21,cv1) EPI0(2,2,acc22,cv2) EPI0(2,3,acc23,cv3)
        EPI0(3,0,acc30,cv0) EPI0(3,1,acc31,cv1) EPI0(3,2,acc32,cv2) EPI0(3,3,acc33,cv3)
    }
    ISSUE(W1, 0);
    __syncthreads();                                  // C0 visible + W1 slab0 ready
    RING(W1);
    {   // epi1: C1 = silu(acc + P[b,i] + Q[b,j]) -> aL
        float Pv0 = Pbuf[(size_t)bi * 512 + wn +  0 + ml];
        float Pv1 = Pbuf[(size_t)bi * 512 + wn + 16 + ml];
        float Pv2 = Pbuf[(size_t)bi * 512 + wn + 32 + ml];
        float Pv3 = Pbuf[(size_t)bi * 512 + wn + 48 + ml];
        EPI1(0,0,acc00,Pv0) EPI1(0,1,acc01,Pv1) EPI1(0,2,acc02,Pv2) EPI1(0,3,acc03,Pv3)
        EPI1(1,0,acc10,Pv0) EPI1(1,1,acc11,Pv1) EPI1(1,2,acc12,Pv2) EPI1(1,3,acc13,Pv3)
        EPI1(2,0,acc20,Pv0) EPI1(2,1,acc21,Pv1) EPI1(2,2,acc22,Pv2) EPI1(2,3,acc23,Pv3)
        EPI1(3,0,acc30,Pv0) EPI1(3,1,acc31,Pv1) EPI1(3,2,acc32,Pv2) EPI1(3,3,acc33,Pv3)
    }
    ISSUE(W2, 0);
    __syncthreads();                                  // C1 visible + W2 slab0 ready
    RING(W2);
    {   // epi2: out_e = acc + b_ev2 ; v2 += anorm-weighted j-sum (atomic)
        float* awl = (float*)bL;                      // 2048 floats; ring fully drained
        ((float4*)awl)[t] = ((const float4*)(anorm + (size_t)bi * 4096 + half * 2048))[t];
        __syncthreads();
        float bv0 = b_ev2[wn +  0 + ml];
        float bv1 = b_ev2[wn + 16 + ml];
        float bv2 = b_ev2[wn + 32 + ml];
        float bv3 = b_ev2[wn + 48 + ml];
        float p0 = 0.f, p1 = 0.f, p2 = 0.f, p3 = 0.f;
        EPI2(0,0,acc00,bv0,p0) EPI2(0,1,acc01,bv1,p1) EPI2(0,2,acc02,bv2,p2) EPI2(0,3,acc03,bv3,p3)
        EPI2(1,0,acc10,bv0,p0) EPI2(1,1,acc11,bv1,p1) EPI2(1,2,acc12,bv2,p2) EPI2(1,3,acc13,bv3,p3)
        EPI2(2,0,acc20,bv0,p0) EPI2(2,1,acc21,bv1,p1) EPI2(2,2,acc22,bv2,p2) EPI2(2,3,acc23,bv3,p3)
        EPI2(3,0,acc30,bv0,p0) EPI2(3,1,acc31,bv1,p1) EPI2(3,2,acc32,bv2,p2) EPI2(3,3,acc33,bv3,p3)
        { float p = p0; p += __shfl_down(p, 32); p += __shfl_down(p, 16);
          if (lane < 16) atomicAdd(v2buf + (size_t)bi * 512 + wn +  0 + ml, p); }
        { float p = p1; p += __shfl_down(p, 32); p += __shfl_down(p, 16);
          if (lane < 16) atomicAdd(v2buf + (size_t)bi * 512 + wn + 16 + ml, p); }
        { float p = p2; p += __shfl_down(p, 32); p += __shfl_down(p, 16);
          if (lane < 16) atomicAdd(v2buf + (size_t)bi * 512 + wn + 32 + ml, p); }
        { float p = p3; p += __shfl_down(p, 32); p += __shfl_down(p, 16);
          if (lane < 16) atomicAdd(v2buf + (size_t)bi * 512 + wn + 48 + ml, p); }
    }
}

// ---------------- fused masked max-pool + output projection ----------------
__global__ __launch_bounds__(1024) void k_out(const float* v2, const float* vmask,
                                              const float* W_out, const float* b_out,
                                              float* out) {
    __shared__ float rv[2][512];          // this block's 2 rows
    __shared__ float vm[128];
    __shared__ float pm[2][512];
    __shared__ float pooled[512];
    __shared__ float red[2][2][256];      // [kc][row][col]
    __shared__ float cpred[2][256];
    int t = threadIdx.x;
    int r0 = blockIdx.x * 2, b = r0 >> 7;
    if (t < 128) vm[t] = -1e9f * (1.f - vmask[b*128 + t]);
    rv[t >> 9][t & 511] = v2[(size_t)(r0 + (t >> 9)) * 512 + (t & 511)];
    __syncthreads();
    {   // masked max-pool: col = t&511, row-chunk rc = t>>9 (64 rows each)
        int col = t & 511, rc = t >> 9;
        int i0 = rc * 64;
        const float* src = v2 + ((size_t)(b*128 + i0)) * 512 + col;
        float m = -1e30f;
        #pragma unroll 8
        for (int i = 0; i < 64; ++i)
            m = fmaxf(m, src[(size_t)i * 512] + vm[i0 + i]);
        pm[rc][col] = m;
    }
    __syncthreads();
    if (t < 512) pooled[t] = fmaxf(pm[0][t], pm[1][t]);
    __syncthreads();
    {   // projection: col = t&255, k-chunk kc = t>>8
        int col = t & 255, kc = t >> 8;
        if (kc < 2) {
            int k0 = kc * 256;
            float a0 = 0.f, a1 = 0.f;
            #pragma unroll 8
            for (int k = 0; k < 256; ++k) {
                float w = W_out[(size_t)(k0 + k) * 256 + col];
                a0 += rv[0][k0 + k] * w;
                a1 += rv[1][k0 + k] * w;
            }
            red[kc][0][col] = a0;
            red[kc][1][col] = a1;
        } else {
            int d0 = (kc - 2) * 256;
            float cp = 0.f;
            #pragma unroll 8
            for (int d = 0; d < 256; ++d)
                cp += pooled[d0 + d] * W_out[(size_t)(512 + d0 + d) * 256 + col];
            cpred[kc - 2][col] = cp;
        }
    }
    __syncthreads();
    if (t < 512) {
        int row = t >> 8, c = t & 255;
        float x = red[0][row][c] + red[1][row][c]
                + cpred[0][c] + cpred[1][c] + b_out[c];
        out[(size_t)(r0 + row) * 256 + c] = siluf(x);
    }
}

extern "C" void kernel_launch(void* const* d_in, const int* in_sizes, int n_in,
                              void* d_out, int out_size, void* d_ws, size_t ws_size,
                              hipStream_t stream) {
    const float* v_f    = (const float*)d_in[0];
    const float* e_f    = (const float*)d_in[1];
    const float* p_pe   = (const float*)d_in[2];
    const float* t_pe   = (const float*)d_in[3];
    const float* emask  = (const float*)d_in[4];
    const float* vmask  = (const float*)d_in[5];
    const float* W_vpe  = (const float*)d_in[6];
    const float* b_vpe  = (const float*)d_in[7];
    const float* W_epe  = (const float*)d_in[8];
    const float* b_epe  = (const float*)d_in[9];
    const float* W_ev1  = (const float*)d_in[10];
    const float* b_ev1  = (const float*)d_in[11];
    const float* W_ev2  = (const float*)d_in[12];
    const float* b_ev2  = (const float*)d_in[13];
    const float* W_q    = (const float*)d_in[14];
    const float* b_q    = (const float*)d_in[15];
    const float* W_k    = (const float*)d_in[16];
    const float* b_k    = (const float*)d_in[17];
    const float* W_self = (const float*)d_in[18];
    const float* b_self = (const float*)d_in[19];
    const float* W_out  = (const float*)d_in[20];
    const float* b_out  = (const float*)d_in[21];

    float* out_v = (float*)d_out;                 // (4,128,256)
    float* out_e = (float*)d_out + 131072;        // (4,16384,512)

    char* w = (char*)d_ws;
    ushort_t* WT_epe = (ushort_t*)w; w += 512*512*2;
    ushort_t* WT_c   = (ushort_t*)w; w += 512*512*2;
    ushort_t* WT_ev2 = (ushort_t*)w; w += 512*512*2;
    float* c_v   = (float*)w; w += 4*256*4;
    float* c_e   = (float*)w; w += 4*512*4;
    float* v     = (float*)w; w += 512*256*4;
    float* qbuf  = (float*)w; w += 512*512*4;
    float* kbuf  = (float*)w; w += 512*512*4;
    float* Pbuf  = (float*)w; w += 512*512*4;
    float* Qbuf  = (float*)w; w += 512*512*4;
    float* v2buf = (float*)w; w += 512*512*4;
    float* anorm = (float*)w; w += (size_t)4*128*128*32*4;   // 8 MB

    k_pt<<<dim3(512, 4), 256, 0, stream>>>(W_epe, W_ev1, W_ev2, t_pe, W_vpe, b_vpe, b_epe,
                                           WT_epe, WT_c, WT_ev2, c_v, c_e);
    k_node_v<<<128, 256, 0, stream>>>(v_f, p_pe, W_vpe, c_v, v);
    k_node_proj<<<dim3(128, 5), 256, 0, stream>>>(v, W_q, b_q, W_k, b_k, W_self, b_self,
                                                  W_ev1, b_ev1, qbuf, kbuf, v2buf, Pbuf, Qbuf);
    k_attw<<<512, 256, 0, stream>>>(qbuf, kbuf, emask, anorm);
    k_chain<<<1024, 512, 0, stream>>>(e_f, WT_epe, WT_c, WT_ev2, c_e, Pbuf, Qbuf,
                                      b_ev2, anorm, out_e, v2buf);
    k_out<<<256, 1024, 0, stream>>>(v2buf, vmask, W_out, b_out, out_v);
}